// Round 12
// baseline (20167.085 us; speedup 1.0000x reference)
//
#include <hip/hip_runtime.h>

#define DEVI __device__ __forceinline__

// ---------------- zero state ----------------
__global__ __launch_bounds__(256) void zero_state(float* __restrict__ s) {
  long i = ((long)blockIdx.x * 256 + threadIdx.x) * 4;
  *(float4*)(s + i) = make_float4(0.f, 0.f, 0.f, 0.f);
}

// ---------------- token-shift mix into chunk buffer [B][Tc][C], scalar ------
__global__ __launch_bounds__(256) void mix_one(
    const float* __restrict__ x, const float* __restrict__ coef,
    float* __restrict__ out, int t0, int tcl) {
  long i = (long)blockIdx.x * 256 + threadIdx.x;  // chunk elem idx
  int c = (int)(i & 2047);
  long mrow = i >> 11;
  int b = (int)(mrow >> tcl);
  int tloc = (int)(mrow & ((1L << tcl) - 1));
  int t = t0 + tloc;
  long g = (((long)b << 11) + t) * 2048 + c;
  float xv = x[g];
  float xp = (t > 0) ? x[g - 2048] : 0.f;
  out[i] = xv + (xp - xv) * coef[c];
}

// ---------------- plain vector GEMM, f32, 128x128 tile, BK=8 ----------------
// C[M][N] = A[M][K] @ B[K][N]; B in NATURAL [K][N] layout.
// Cross-validated in R6 (MFMA) vs R7 (VALU): core + epilogue indexing agree.
#define EPI_F32 0
#define EPI_TANH 1
#define EPI_DECAY 2
#define EPI_SIGB 3
#define EPI_VMIX 4
#define EPI_SIG 5
#define EPI_F32G 6

template <int EPI>
__global__ __launch_bounds__(256) void vgemm(
    const float* __restrict__ A, const float* __restrict__ B,
    float* __restrict__ Cv, int M, int N, int K,
    const float* __restrict__ aux0, const float* __restrict__ aux1,
    const float* __restrict__ aux2, int t0, int tcl) {
  __shared__ float As[8][128];  // [k][m]
  __shared__ float Bs[8][128];  // [k][n]
  const int tid = threadIdx.x;
  const int tm = tid & 15, tn = tid >> 4;
  const long m0 = (long)blockIdx.x * 128, n0 = (long)blockIdx.y * 128;
  float acc[8][8];
#pragma unroll
  for (int i = 0; i < 8; i++)
#pragma unroll
    for (int j = 0; j < 8; j++) acc[i][j] = 0.f;

  const int ar = tid >> 1, akc = (tid & 1) * 4;
  const int bkr = tid >> 5, bnc = (tid & 31) * 4;

  for (int k0 = 0; k0 < K; k0 += 8) {
    float4 av = *(const float4*)&A[(m0 + ar) * (long)K + k0 + akc];
    As[akc + 0][ar] = av.x; As[akc + 1][ar] = av.y;
    As[akc + 2][ar] = av.z; As[akc + 3][ar] = av.w;
    {
      long n = n0 + bnc;
      float4 bv = make_float4(0.f, 0.f, 0.f, 0.f);
      if (n + 3 < N) {
        bv = *(const float4*)&B[(k0 + bkr) * (long)N + n];
      } else {
        if (n + 0 < N) bv.x = B[(k0 + bkr) * (long)N + n + 0];
        if (n + 1 < N) bv.y = B[(k0 + bkr) * (long)N + n + 1];
        if (n + 2 < N) bv.z = B[(k0 + bkr) * (long)N + n + 2];
      }
      *(float4*)&Bs[bkr][bnc] = bv;
    }
    __syncthreads();
#pragma unroll
    for (int kk = 0; kk < 8; ++kk) {
      float4 a0v = *(const float4*)&As[kk][tm * 8];
      float4 a1v = *(const float4*)&As[kk][tm * 8 + 4];
      float4 b0v = *(const float4*)&Bs[kk][tn * 8];
      float4 b1v = *(const float4*)&Bs[kk][tn * 8 + 4];
      float am[8] = {a0v.x, a0v.y, a0v.z, a0v.w, a1v.x, a1v.y, a1v.z, a1v.w};
      float bn[8] = {b0v.x, b0v.y, b0v.z, b0v.w, b1v.x, b1v.y, b1v.z, b1v.w};
#pragma unroll
      for (int i = 0; i < 8; i++)
#pragma unroll
        for (int j = 0; j < 8; j++) acc[i][j] = fmaf(am[i], bn[j], acc[i][j]);
    }
    __syncthreads();
  }

#pragma unroll
  for (int i = 0; i < 8; i++) {
#pragma unroll
    for (int j = 0; j < 8; j++) {
      long row = m0 + tm * 8 + i;
      long col = n0 + tn * 8 + j;
      if (col >= N) continue;
      float v = acc[i][j];
      long idx = row * N + col;
      if (EPI == EPI_F32) {
        Cv[idx] = v;
      } else if (EPI == EPI_TANH) {
        Cv[idx] = tanhf(v);
      } else if (EPI == EPI_DECAY) {
        float val = v + aux0[col];
        float z = -val;
        float sp = fmaxf(z, 0.f) + log1pf(__expf(-fabsf(z)));
        Cv[idx] = __expf(-__expf(-sp - 0.5f));
      } else if (EPI == EPI_SIGB) {
        Cv[idx] = 1.f / (1.f + __expf(-(v + aux0[col])));
      } else if (EPI == EPI_VMIX) {
        float vm = 1.f / (1.f + __expf(-(v + aux0[col])));
        long grow = (((long)(row >> tcl)) << 11) + t0 + (row & ((1L << tcl) - 1));
        float vcur = aux1[idx];
        Cv[idx] = vcur + (aux2[grow * 2048 + col] - vcur) * vm;
      } else if (EPI == EPI_SIG) {
        Cv[idx] = 1.f / (1.f + __expf(-v));
      } else if (EPI == EPI_F32G) {
        long grow = (((long)(row >> tcl)) << 11) + t0 + (row & ((1L << tcl) - 1));
        Cv[grow * 2048 + col] = v;
      }
    }
  }
}

// ---------------- kk normalize / k update — LDS-serial reduction ------------
__global__ __launch_bounds__(256) void kkprep(
    float* __restrict__ k, const float* __restrict__ a, float* __restrict__ kk,
    const float* __restrict__ kkc, const float* __restrict__ kac) {
  __shared__ float red[4][64];
  int wid = threadIdx.x >> 6, lane = threadIdx.x & 63;
  long gid = (long)blockIdx.x * 4 + wid;
  long m = gid >> 5;
  int h = (int)(gid & 31);
  int c = h * 64 + lane;
  long idx = m * 2048 + c;
  float kv = k[idx], av = a[idx];
  float kr = kv * kkc[c];
  red[wid][lane] = kr * kr;
  __syncthreads();
  float ss = 0.f;
#pragma unroll
  for (int j = 0; j < 64; j++) ss += red[wid][j];
  float nrm = fmaxf(sqrtf(ss), 1e-12f);
  kk[idx] = kr / nrm;
  k[idx] = kv * (1.f + (av - 1.f) * kac[c]);
}

// ---------------- WKV-7 scan — one wave per (b,h), lane = state row ---------
__global__ __launch_bounds__(64) void wkv_scan(
    const float* __restrict__ rp, const float* __restrict__ kp,
    const float* __restrict__ vp, const float* __restrict__ kkp,
    const float* __restrict__ ap, const float* __restrict__ wp,
    float* __restrict__ y, float* __restrict__ state, int tcl) {
  __shared__ float lds[6][64];  // r,k,v,kk,a,w
  const int bh = blockIdx.x;            // b*32 + h, 128 total
  const int lane = threadIdx.x;         // state row i
  const long baseC = (((long)(bh >> 5)) << tcl) * 2048 + (long)(bh & 31) * 64;
  const int Tc = 1 << tcl;

  float s[64];
  const long soff = ((long)bh * 64 + lane) * 64;
#pragma unroll
  for (int j = 0; j < 64; j++) s[j] = state[soff + j];

  for (int tl = 0; tl < Tc; ++tl) {
    long go = baseC + (long)tl * 2048 + lane;
    lds[0][lane] = rp[go];
    lds[1][lane] = kp[go];
    lds[2][lane] = vp[go];
    lds[3][lane] = kkp[go];
    lds[4][lane] = ap[go];
    lds[5][lane] = wp[go];
    __syncthreads();
    float sa = 0.f;
#pragma unroll
    for (int j = 0; j < 64; j++) sa += s[j] * lds[3][j];
    sa = -sa;
    float vi = lds[2][lane];
    float yv = 0.f;
#pragma unroll
    for (int j = 0; j < 64; j++) {
      s[j] = fmaf(s[j], lds[5][j], fmaf(sa, lds[3][j] * lds[4][j], vi * lds[1][j]));
      yv = fmaf(s[j], lds[0][j], yv);
    }
    y[go] = yv;
    __syncthreads();
  }
#pragma unroll
  for (int j = 0; j < 64; j++) state[soff + j] = s[j];
}

// ---------------- group-norm + bonus + gate — LDS-serial reductions ---------
__global__ __launch_bounds__(256) void post(
    const float* __restrict__ y, const float* __restrict__ r,
    const float* __restrict__ k, const float* __restrict__ v,
    const float* __restrict__ g, const float* __restrict__ rk,
    const float* __restrict__ lnw, const float* __restrict__ lnb,
    float* __restrict__ og) {
  __shared__ float red[4][64];
  int wid = threadIdx.x >> 6, lane = threadIdx.x & 63;
  long gid = (long)blockIdx.x * 4 + wid;
  long m = gid >> 5;
  int h = (int)(gid & 31);
  int c = h * 64 + lane;
  long idx = m * 2048 + c;
  float yv = y[idx];
  red[wid][lane] = yv;
  __syncthreads();
  float sum = 0.f;
#pragma unroll
  for (int j = 0; j < 64; j++) sum += red[wid][j];
  float mu = sum * (1.f / 64.f);
  float d = yv - mu;
  __syncthreads();
  red[wid][lane] = d * d;
  __syncthreads();
  float vs = 0.f;
#pragma unroll
  for (int j = 0; j < 64; j++) vs += red[wid][j];
  float var = vs * (1.f / 64.f);
  float rstd = rsqrtf(var + 64e-5f);
  float yn = d * rstd * lnw[c] + lnb[c];
  __syncthreads();
  red[wid][lane] = r[idx] * k[idx] * rk[c];
  __syncthreads();
  float bsum = 0.f;
#pragma unroll
  for (int j = 0; j < 64; j++) bsum += red[wid][j];
  og[idx] = (yn + bsum * v[idx]) * g[idx];
}

// ---------------- workspace plan (all f32) ----------------
struct WSP {
  float *tw, *ta, *tv, *tg;
  float *mixb, *gb, *ab, *vb, *kb, *rb, *kkb, *wb;
  float* state;
};

static size_t plan_ws(char* base, long Tc, WSP& o) {
  char* p = base;
  auto al = [&](size_t b) -> char* {
    char* r = p; p += (b + 255) & ~(size_t)255; return r;
  };
  const long C = 2048, Mc = 4 * Tc;
  o.tw = (float*)al(Mc * 96 * 4);  o.ta = (float*)al(Mc * 96 * 4);
  o.tv = (float*)al(Mc * 64 * 4);  o.tg = (float*)al(Mc * 256 * 4);
  o.mixb = (float*)al(Mc * C * 4);
  o.gb = (float*)al(Mc * C * 4);   o.ab = (float*)al(Mc * C * 4);
  o.vb = (float*)al(Mc * C * 4);   o.kb = (float*)al(Mc * C * 4);
  o.rb = (float*)al(Mc * C * 4);   o.kkb = (float*)al(Mc * C * 4);
  o.wb = (float*)al(Mc * C * 4);
  o.state = (float*)al(128L * 64 * 64 * 4);  // 2 MB
  return (size_t)(p - base);
}

// ---------------- launcher ----------------
extern "C" void kernel_launch(void* const* d_in, const int* in_sizes, int n_in,
                              void* d_out, int out_size, void* d_ws, size_t ws_size,
                              hipStream_t stream) {
  (void)in_sizes; (void)n_in; (void)out_size;
  const float* x      = (const float*)d_in[0];
  const float* vfirst = (const float*)d_in[1];
  const float* x_r = (const float*)d_in[2];
  const float* x_w = (const float*)d_in[3];
  const float* x_k = (const float*)d_in[4];
  const float* x_v = (const float*)d_in[5];
  const float* x_a = (const float*)d_in[6];
  const float* x_g = (const float*)d_in[7];
  const float* w0 = (const float*)d_in[8];
  const float* w1 = (const float*)d_in[9];
  const float* w2 = (const float*)d_in[10];
  const float* a0 = (const float*)d_in[11];
  const float* a1 = (const float*)d_in[12];
  const float* a2 = (const float*)d_in[13];
  const float* v0 = (const float*)d_in[14];
  const float* v1 = (const float*)d_in[15];
  const float* v2 = (const float*)d_in[16];
  const float* g1 = (const float*)d_in[17];
  const float* g2 = (const float*)d_in[18];
  const float* k_k = (const float*)d_in[19];
  const float* k_a = (const float*)d_in[20];
  const float* r_k = (const float*)d_in[21];
  const float* W_r = (const float*)d_in[22];
  const float* W_k = (const float*)d_in[23];
  const float* W_v = (const float*)d_in[24];
  const float* W_o = (const float*)d_in[25];
  const float* ln_w = (const float*)d_in[26];
  const float* ln_b = (const float*)d_in[27];
  float* out = (float*)d_out;

  const int C = 2048, T = 2048;

  WSP W;
  int tcl = -1;
  for (int cand = 11; cand >= 6; --cand) {
    if (plan_ws((char*)d_ws, 1L << cand, W) <= ws_size) { tcl = cand; break; }
  }
  if (tcl < 0) return;  // ws too small: all-zeros signature (absmax ~= 21.6)
  plan_ws((char*)d_ws, 1L << tcl, W);
  const int Tc = 1 << tcl, Mc = 4 * Tc, gx = Mc / 128;

  zero_state<<<512, 256, 0, stream>>>(W.state);

  for (int t0 = 0; t0 < T; t0 += Tc) {
    // g-path: g = sigmoid(xg @ g1) @ g2   (sigmoid BETWEEN the matmuls!)
    mix_one<<<Mc * 8, 256, 0, stream>>>(x, x_g, W.mixb, t0, tcl);
    vgemm<EPI_SIG><<<dim3(gx, 2), 256, 0, stream>>>(W.mixb, g1, W.tg, Mc, 256, C, nullptr, nullptr, nullptr, 0, 0);
    vgemm<EPI_F32><<<dim3(gx, 16), 256, 0, stream>>>(W.tg, g2, W.gb, Mc, C, 256, nullptr, nullptr, nullptr, 0, 0);
    // w-path: w_raw = tanh(xw @ w1) @ w2 + w0 -> soft-clamped decay
    mix_one<<<Mc * 8, 256, 0, stream>>>(x, x_w, W.mixb, t0, tcl);
    vgemm<EPI_TANH><<<dim3(gx, 1), 256, 0, stream>>>(W.mixb, w1, W.tw, Mc, 96, C, nullptr, nullptr, nullptr, 0, 0);
    vgemm<EPI_DECAY><<<dim3(gx, 16), 256, 0, stream>>>(W.tw, w2, W.wb, Mc, C, 96, w0, nullptr, nullptr, 0, 0);
    // a-path: a = sigmoid((xa @ a1) @ a2 + a0)
    mix_one<<<Mc * 8, 256, 0, stream>>>(x, x_a, W.mixb, t0, tcl);
    vgemm<EPI_F32><<<dim3(gx, 1), 256, 0, stream>>>(W.mixb, a1, W.ta, Mc, 96, C, nullptr, nullptr, nullptr, 0, 0);
    vgemm<EPI_SIGB><<<dim3(gx, 16), 256, 0, stream>>>(W.ta, a2, W.ab, Mc, C, 96, a0, nullptr, nullptr, 0, 0);
    // v-path
    mix_one<<<Mc * 8, 256, 0, stream>>>(x, x_v, W.mixb, t0, tcl);
    vgemm<EPI_F32><<<dim3(gx, 1), 256, 0, stream>>>(W.mixb, v1, W.tv, Mc, 64, C, nullptr, nullptr, nullptr, 0, 0);
    vgemm<EPI_F32><<<dim3(gx, 16), 256, 0, stream>>>(W.mixb, W_v, W.vb, Mc, C, C, nullptr, nullptr, nullptr, 0, 0);
    vgemm<EPI_VMIX><<<dim3(gx, 16), 256, 0, stream>>>(W.tv, v2, W.vb, Mc, C, 64, v0, W.vb, vfirst, t0, tcl);
    // k-path
    mix_one<<<Mc * 8, 256, 0, stream>>>(x, x_k, W.mixb, t0, tcl);
    vgemm<EPI_F32><<<dim3(gx, 16), 256, 0, stream>>>(W.mixb, W_k, W.kb, Mc, C, C, nullptr, nullptr, nullptr, 0, 0);
    // r-path
    mix_one<<<Mc * 8, 256, 0, stream>>>(x, x_r, W.mixb, t0, tcl);
    vgemm<EPI_F32><<<dim3(gx, 16), 256, 0, stream>>>(W.mixb, W_r, W.rb, Mc, C, C, nullptr, nullptr, nullptr, 0, 0);

    // kk normalize + k update (in place)
    kkprep<<<Mc * 8, 256, 0, stream>>>(W.kb, W.ab, W.kkb, k_k, k_a);

    // scan (y aliases mixb — dead after r GEMM; kka = kk*a in-scan)
    float* ych = W.mixb;
    wkv_scan<<<128, 64, 0, stream>>>(W.rb, W.kb, W.vb, W.kkb, W.ab, W.wb,
                                     ych, W.state, tcl);

    // group-norm + bonus + gate (og aliases wb — dead after scan)
    float* og = W.wb;
    post<<<Mc * 8, 256, 0, stream>>>(ych, W.rb, W.kb, W.vb, W.gb, r_k, ln_w, ln_b, og);

    // output projection -> global rows of out
    vgemm<EPI_F32G><<<dim3(gx, 16), 256, 0, stream>>>(og, W_o, out, Mc, C, C, nullptr, nullptr, nullptr, t0, tcl);
  }
}